// Round 9
// baseline (541.611 us; speedup 1.0000x reference)
//
#include <hip/hip_runtime.h>

// gcd(a,b)*W_gcd -> out[0..N), (a%p)*W_mod -> out[N..2N)
// a,b in [0,1e6), p in [1,1e6): all values < 2^20, nonnegative.
//
// GCD: Stein, 4-way interleaved. Inner step = 4 VALU inst: v_ffbl_b32
//   (-1 for 0; shifts HW-mask the amount so 0>>31==0), v_lshrrev,
//   v_sad_u32 (|a-b|), v_min_u32. (0,g_odd) is a FIXED POINT of the step,
//   so overshooting is free.
// STRUCTURE (the R8 change): R4 (44 fixed passes, zero checks) ran at 89%
//   VALUBusy; every __any-early-exit variant runs at 64-75% — the checks
//   serialize vcc->s_cbranch every 8 passes and waves are phase-locked, so
//   the bubbles don't hide. Fix: 32 FIXED passes straight-line (realized
//   wave-max ~30-36), then a check-FIRST cleanup loop that usually exits
//   on its first check. Iteration count ~= R5, check count 4-5 -> 1-2,
//   uninterrupted issue for the bulk.
// MOD: exact fp32 (ints < 2^20): q=rint(a*rcp(p)) in {floor,floor+1},
//   r=fma(-q,p,a) exact, single fixup. Stored BEFORE the GCD loop.
// (Asm-prefetch pipelining removed: nulled twice, R6/R7.)

typedef int v4i __attribute__((ext_vector_type(4)));

__device__ __forceinline__ unsigned ffbl(unsigned x) {
    unsigned r;
    asm("v_ffbl_b32 %0, %1" : "=v"(r) : "v"(x));   // -1 if x==0
    return r;
}

__global__ __launch_bounds__(256) void ntb_kernel(
    const v4i* __restrict__ a4, const v4i* __restrict__ b4,
    const v4i* __restrict__ p4,
    const float* __restrict__ Wg, const float* __restrict__ Wm,
    float4* __restrict__ gcd_out, float4* __restrict__ mod_out, int n4)
{
    const float wg = Wg[0];
    const float wm = Wm[0];
    const int stride = gridDim.x * blockDim.x;

    for (int i = blockIdx.x * blockDim.x + threadIdx.x; i < n4; i += stride) {
        const v4i av = a4[i];
        const v4i bv = b4[i];
        const v4i pv = p4[i];

        // ---- mod branch first: store overlaps the GCD loop ----
        {
            float mm[4];
            #pragma unroll
            for (int v = 0; v < 4; ++v) {
                const float af = (float)(unsigned)av[v];
                const float pf = (float)(unsigned)pv[v];
                const float q  = rintf(af * __builtin_amdgcn_rcpf(pf)); // {floor,floor+1}
                float r = fmaf(-q, pf, af);                             // exact, in (-p,p)
                r += (r < 0.0f) ? pf : 0.0f;
                mm[v] = r * wm;
            }
            float4 m; m.x = mm[0]; m.y = mm[1]; m.z = mm[2]; m.w = mm[3];
            mod_out[i] = m;
        }

        // ---- GCD ----
        unsigned A[4], B[4], S[4];
        #pragma unroll
        for (int v = 0; v < 4; ++v) {
            A[v] = (unsigned)av[v];
            B[v] = (unsigned)bv[v];
            S[v] = ffbl(A[v] | B[v]);            // &31 folds into the final shift
            A[v] >>= (ffbl(A[v]) & 31u);         // A=0 -> stays 0
        }

        // 32 fixed passes, straight-line, no checks (R4-style issue stream).
        #pragma unroll
        for (int it = 0; it < 32; ++it) {
            #pragma unroll
            for (int v = 0; v < 4; ++v) {
                const unsigned b  = B[v] >> (ffbl(B[v]) & 31u); // 0 -> 0
                const unsigned nb = __usad(A[v], b, 0u);        // |A - b|
                A[v] = min(A[v], b);
                B[v] = nb;
            }
        }

        // Check-first cleanup: usually exits on the first check.
        while (__any((A[0] | A[1] | A[2] | A[3]) != 0u)) {
            #pragma unroll
            for (int it = 0; it < 8; ++it) {
                #pragma unroll
                for (int v = 0; v < 4; ++v) {
                    const unsigned b  = B[v] >> (ffbl(B[v]) & 31u);
                    const unsigned nb = __usad(A[v], b, 0u);
                    A[v] = min(A[v], b);
                    B[v] = nb;
                }
            }
        }

        float4 g;
        g.x = (float)((A[0] | B[0]) << (S[0] & 31u)) * wg;
        g.y = (float)((A[1] | B[1]) << (S[1] & 31u)) * wg;
        g.z = (float)((A[2] | B[2]) << (S[2] & 31u)) * wg;
        g.w = (float)((A[3] | B[3]) << (S[3] & 31u)) * wg;
        gcd_out[i] = g;
    }
}

extern "C" void kernel_launch(void* const* d_in, const int* in_sizes, int n_in,
                              void* d_out, int out_size, void* d_ws, size_t ws_size,
                              hipStream_t stream) {
    const int n  = in_sizes[0];   // 2^25
    const int n4 = n >> 2;

    const v4i* a4 = (const v4i*)d_in[0];
    const v4i* b4 = (const v4i*)d_in[1];
    const v4i* p4 = (const v4i*)d_in[2];
    const float* Wg = (const float*)d_in[3];
    const float* Wm = (const float*)d_in[4];

    float* out = (float*)d_out;
    float4* gcd_out = (float4*)out;        // first N floats
    float4* mod_out = (float4*)(out + n);  // second N floats

    const int block = 256;
    const int grid  = 8192;  // R5's best config: 4 groups/thread

    ntb_kernel<<<grid, block, 0, stream>>>(a4, b4, p4, Wg, Wm, gcd_out, mod_out, n4);
}

// Round 10
// 524.850 us; speedup vs baseline: 1.0319x; 1.0319x over previous
//
#include <hip/hip_runtime.h>

// gcd(a,b)*W_gcd -> out[0..N), (a%p)*W_mod -> out[N..2N)
// a,b in [0,1e6), p in [1,1e6): all values < 2^20, nonnegative.
//
// GCD: Stein, 4-way interleaved. Inner step = 4 VALU inst: v_ffbl_b32
//   (-1 for 0; shifts HW-mask the amount so 0>>31==0), v_lshrrev,
//   v_sad_u32 (|a-b|), v_min_u32. (0,g_odd) is a FIXED POINT of the step,
//   so overshooting is free.
// STRUCTURE (R10): cost model calibrated on R4/R5/R9:
//   wall = F(~83us) + 3.6us/pass + 2.5us/check, realized wave-max <= ~24.
//   (a) ONE GROUP PER THREAD (grid = n4/256 exactly): no grid-stride loop,
//       so no per-thread sequential group boundaries -> the convoyed
//       load-stall blob (bulk of F) is paid once per wave, and block
//       launch staggering interleaves different waves' stalls.
//       Trend: 16 grp/thr=190us, 4/thr=177us -> 1/thr.
//   (b) fixed-16 straight-line passes (wave-max always >16), then
//       check-every-8 cleanup: ~24 executed passes like R5 but 2 checks
//       instead of 3, uninterrupted issue for the first 16 (R9 showed
//       checks cost ~2.5us each in bubbles).
// MOD: exact fp32 (ints < 2^20): q=rint(a*rcp(p)) in {floor,floor+1},
//   r=fma(-q,p,a) exact, single fixup. Stored BEFORE the GCD loop.

typedef int v4i __attribute__((ext_vector_type(4)));

__device__ __forceinline__ unsigned ffbl(unsigned x) {
    unsigned r;
    asm("v_ffbl_b32 %0, %1" : "=v"(r) : "v"(x));   // -1 if x==0
    return r;
}

__global__ __launch_bounds__(256) void ntb_kernel(
    const v4i* __restrict__ a4, const v4i* __restrict__ b4,
    const v4i* __restrict__ p4,
    const float* __restrict__ Wg, const float* __restrict__ Wm,
    float4* __restrict__ gcd_out, float4* __restrict__ mod_out, int n4)
{
    const int i = blockIdx.x * blockDim.x + threadIdx.x;
    if (i >= n4) return;

    const float wg = Wg[0];
    const float wm = Wm[0];

    const v4i av = a4[i];
    const v4i bv = b4[i];
    const v4i pv = p4[i];

    // ---- mod branch first: store overlaps the GCD loop ----
    {
        float mm[4];
        #pragma unroll
        for (int v = 0; v < 4; ++v) {
            const float af = (float)(unsigned)av[v];
            const float pf = (float)(unsigned)pv[v];
            const float q  = rintf(af * __builtin_amdgcn_rcpf(pf)); // {floor,floor+1}
            float r = fmaf(-q, pf, af);                             // exact, in (-p,p)
            r += (r < 0.0f) ? pf : 0.0f;
            mm[v] = r * wm;
        }
        float4 m; m.x = mm[0]; m.y = mm[1]; m.z = mm[2]; m.w = mm[3];
        mod_out[i] = m;
    }

    // ---- GCD ----
    unsigned A[4], B[4], S[4];
    #pragma unroll
    for (int v = 0; v < 4; ++v) {
        A[v] = (unsigned)av[v];
        B[v] = (unsigned)bv[v];
        S[v] = ffbl(A[v] | B[v]);            // &31 folds into the final shift
        A[v] >>= (ffbl(A[v]) & 31u);         // A=0 -> stays 0
    }

    // 16 fixed passes, straight-line, no checks (wave-max is always > 16).
    #pragma unroll
    for (int it = 0; it < 16; ++it) {
        #pragma unroll
        for (int v = 0; v < 4; ++v) {
            const unsigned b  = B[v] >> (ffbl(B[v]) & 31u); // 0 -> 0
            const unsigned nb = __usad(A[v], b, 0u);        // |A - b|
            A[v] = min(A[v], b);
            B[v] = nb;
        }
    }

    // Cleanup: check first, then 8 passes at a time (typically 1-2 rounds).
    while (__any((A[0] | A[1] | A[2] | A[3]) != 0u)) {
        #pragma unroll
        for (int it = 0; it < 8; ++it) {
            #pragma unroll
            for (int v = 0; v < 4; ++v) {
                const unsigned b  = B[v] >> (ffbl(B[v]) & 31u);
                const unsigned nb = __usad(A[v], b, 0u);
                A[v] = min(A[v], b);
                B[v] = nb;
            }
        }
    }

    float4 g;
    g.x = (float)((A[0] | B[0]) << (S[0] & 31u)) * wg;
    g.y = (float)((A[1] | B[1]) << (S[1] & 31u)) * wg;
    g.z = (float)((A[2] | B[2]) << (S[2] & 31u)) * wg;
    g.w = (float)((A[3] | B[3]) << (S[3] & 31u)) * wg;
    gcd_out[i] = g;
}

extern "C" void kernel_launch(void* const* d_in, const int* in_sizes, int n_in,
                              void* d_out, int out_size, void* d_ws, size_t ws_size,
                              hipStream_t stream) {
    const int n  = in_sizes[0];   // 2^25
    const int n4 = n >> 2;        // 8,388,608 int4 groups

    const v4i* a4 = (const v4i*)d_in[0];
    const v4i* b4 = (const v4i*)d_in[1];
    const v4i* p4 = (const v4i*)d_in[2];
    const float* Wg = (const float*)d_in[3];
    const float* Wm = (const float*)d_in[4];

    float* out = (float*)d_out;
    float4* gcd_out = (float4*)out;        // first N floats
    float4* mod_out = (float4*)(out + n);  // second N floats

    const int block = 256;
    const int grid  = (n4 + block - 1) / block;  // 32768: ONE group per thread

    ntb_kernel<<<grid, block, 0, stream>>>(a4, b4, p4, Wg, Wm, gcd_out, mod_out, n4);
}